// Round 7
// baseline (149.164 us; speedup 1.0000x reference)
//
#include <hip/hip_runtime.h>
#include <math.h>

#pragma clang fp contract(off)

#define B_N   8
#define C_N   3
#define H_IMG 720
#define W_IMG 1280
#define GH    4
#define GW    4
#define CELL_H (H_IMG / GH)   // 180
#define CELL_W (W_IMG / GW)   // 320

// ---------------------------------------------------------------------------
// Kernel 1 (FROZEN numerics — passed R6): netlib sgesv without FMA.
// ---------------------------------------------------------------------------
__global__ void hs_kernel(const float* __restrict__ theta, float* __restrict__ Hs) {
#pragma clang fp contract(off)
    int t = threadIdx.x;
    if (t >= B_N * GH * GW) return;
    int b   = t >> 4;
    int rem = t & 15;
    int i   = rem >> 2;
    int j   = rem & 3;

    float hh = (float)i * 0.5f - 1.0f;
    float ww = (float)j * 0.5f - 1.0f;
    float xs4[4] = { ww, ww + 0.5f, ww, ww + 0.5f };
    float ys4[4] = { hh, hh, hh + 0.5f, hh + 0.5f };
    int ci[4] = { i, i, i + 1, i + 1 };
    int cj[4] = { j, j + 1, j, j + 1 };

    float A[8][8], bv[8];
#pragma unroll
    for (int k = 0; k < 4; ++k) {
        int base = ((b * (GH + 1) + ci[k]) * (GW + 1) + cj[k]) * 2;
        float u = theta[base + 0];
        float v = theta[base + 1];
        float x = xs4[k], y = ys4[k];
        A[k][0] = x;    A[k][1] = y;    A[k][2] = 1.0f;
        A[k][3] = 0.0f; A[k][4] = 0.0f; A[k][5] = 0.0f;
        A[k][6] = -x * u;  A[k][7] = -y * u;
        bv[k] = u;
        A[k+4][0] = 0.0f; A[k+4][1] = 0.0f; A[k+4][2] = 0.0f;
        A[k+4][3] = x;    A[k+4][4] = y;    A[k+4][5] = 1.0f;
        A[k+4][6] = -x * v;  A[k+4][7] = -y * v;
        bv[k+4] = v;
    }
#pragma unroll
    for (int d = 0; d < 8; ++d) A[d][d] = A[d][d] + 1e-4f;

    for (int k = 0; k < 8; ++k) {
        int p = k;
        float pm = fabsf(A[k][k]);
        for (int r = k + 1; r < 8; ++r) {
            float m = fabsf(A[r][k]);
            if (m > pm) { pm = m; p = r; }
        }
        if (p != k) {
            for (int c = 0; c < 8; ++c) {
                float tmp = A[k][c]; A[k][c] = A[p][c]; A[p][c] = tmp;
            }
            float tb = bv[k]; bv[k] = bv[p]; bv[p] = tb;
        }
        float inv = 1.0f / A[k][k];
        for (int r = k + 1; r < 8; ++r) A[r][k] = A[r][k] * inv;
        for (int r = k + 1; r < 8; ++r) {
            float l = A[r][k];
            for (int c = k + 1; c < 8; ++c) A[r][c] = A[r][c] - l * A[k][c];
        }
    }
    for (int k = 0; k < 8; ++k) {
        float bk = bv[k];
        for (int r = k + 1; r < 8; ++r) bv[r] = bv[r] - bk * A[r][k];
    }
    for (int k = 7; k >= 0; --k) {
        bv[k] = bv[k] / A[k][k];
        float bk = bv[k];
        for (int r = 0; r < k; ++r) bv[r] = bv[r] - bk * A[r][k];
    }

    float* o = Hs + t * 9;
#pragma unroll
    for (int k = 0; k < 8; ++k) o[k] = bv[k];
    o[8] = 1.0f;
}

// ---------------------------------------------------------------------------
// Kernel 2: 4 pixels/thread along x (one row, one cell — CELL_W%4==0).
// Per-pixel arithmetic bit-identical to the R6 PASS (JAX-f32 semantics:
// f32 linspace, non-FMA left-assoc einsum, f32 guard/divide/oob/bilinear).
// Only the work mapping and store width changed (float4 stores).
// ---------------------------------------------------------------------------
#define GROUPS_X (W_IMG / 4)   // 320

__global__ __launch_bounds__(256) void warp_kernel(const float* __restrict__ U,
                                                   const float* __restrict__ Hs,
                                                   float* __restrict__ out) {
#pragma clang fp contract(off)
    const int HW = H_IMG * W_IMG;
    int g = blockIdx.x * 256 + threadIdx.x;
    if (g >= B_N * H_IMG * GROUPS_X) return;

    int gxi = g % GROUPS_X;
    int t   = g / GROUPS_X;          // t = b*H + y
    int y   = t % H_IMG;
    int b   = t / H_IMG;
    int xp  = gxi * 4;               // first pixel x of this group

    int ci = y / CELL_H;
    int cj = xp / CELL_W;            // same cell for all 4 px
    const float* Hm = Hs + (((b * GH) + ci) * GW + cj) * 9;
    float h0 = Hm[0], h1 = Hm[1], h2 = Hm[2];
    float h3 = Hm[3], h4 = Hm[4], h5 = Hm[5];
    float h6 = Hm[6], h7 = Hm[7];

    const float DX = 2.0f / 1279.0f;
    const float DY = 2.0f / 719.0f;
    float gy = (y == H_IMG - 1) ? 1.0f : (-1.0f + (float)y * DY);

    float xmv[4], ymv[4], oobv[4];
    float cv0[4], cv1[4], cv2[4];

    const float* Ub = U + (size_t)b * C_N * HW;

#pragma unroll
    for (int k = 0; k < 4; ++k) {
        int x = xp + k;
        float gx = (x == W_IMG - 1) ? 1.0f : (-1.0f + (float)x * DX);

        // einsum f32, non-FMA, left-assoc (FROZEN)
        float X = h0 * gx + h1 * gy + h2;
        float Y = h3 * gx + h4 * gy + h5;
        float Z = h6 * gx + h7 * gy + 1.0f;

        float Zg = Z + ((Z >= 0.0f) ? 1e-8f : -1e-8f);
        float xm = X / Zg;
        float ym = Y / Zg;
        xmv[k] = xm;
        ymv[k] = ym;
        oobv[k] = ((xm < -1.0f) | (xm > 1.0f) | (ym < -1.0f) | (ym > 1.0f))
                      ? 1.0f : 0.0f;

        float xf = ((xm + 1.0f) * 1280.0f) * 0.5f;
        float yf = ((ym + 1.0f) * 720.0f) * 0.5f;
        int x0 = (int)floorf(xf);
        int y0 = (int)floorf(yf);
        int x1 = x0 + 1;
        int y1 = y0 + 1;
        x0 = min(max(x0, 0), W_IMG - 1);
        x1 = min(max(x1, 0), W_IMG - 1);
        y0 = min(max(y0, 0), H_IMG - 1);
        y1 = min(max(y1, 0), H_IMG - 1);
        float x0f = (float)x0, x1f = (float)x1;
        float y0f = (float)y0, y1f = (float)y1;
        float wa  = (x1f - xf) * (y1f - yf);
        float wb  = (x1f - xf) * (yf - y0f);
        float wcw = (xf - x0f) * (y1f - yf);
        float wd  = (xf - x0f) * (yf - y0f);

        int ia = y0 * W_IMG + x0;
        int ib = y1 * W_IMG + x0;
        int ic = y0 * W_IMG + x1;
        int id = y1 * W_IMG + x1;

        {
            const float* Uc = Ub;
            cv0[k] = wa * Uc[ia] + wb * Uc[ib] + wcw * Uc[ic] + wd * Uc[id];
        }
        {
            const float* Uc = Ub + (size_t)HW;
            cv1[k] = wa * Uc[ia] + wb * Uc[ib] + wcw * Uc[ic] + wd * Uc[id];
        }
        {
            const float* Uc = Ub + (size_t)(2 * HW);
            cv2[k] = wa * Uc[ia] + wb * Uc[ib] + wcw * Uc[ic] + wd * Uc[id];
        }
    }

    float* out0 = out;
    float* out1 = out + (size_t)B_N * C_N * HW;
    float* out2 = out1 + (size_t)B_N * HW;
    float* out3 = out2 + (size_t)B_N * HW * 2;
    float* out4 = out3 + (size_t)B_N * HW;

    size_t rowbase = (size_t)t * W_IMG + xp;   // pixel index of px 0

    // out0: 3 channel float4 stores
    *reinterpret_cast<float4*>(&out0[(size_t)(b * C_N + 0) * HW + (size_t)y * W_IMG + xp])
        = make_float4(cv0[0], cv0[1], cv0[2], cv0[3]);
    *reinterpret_cast<float4*>(&out0[(size_t)(b * C_N + 1) * HW + (size_t)y * W_IMG + xp])
        = make_float4(cv1[0], cv1[1], cv1[2], cv1[3]);
    *reinterpret_cast<float4*>(&out0[(size_t)(b * C_N + 2) * HW + (size_t)y * W_IMG + xp])
        = make_float4(cv2[0], cv2[1], cv2[2], cv2[3]);

    *reinterpret_cast<float4*>(&out1[rowbase])
        = make_float4(oobv[0], oobv[1], oobv[2], oobv[3]);

    // out2: interleaved (x,y) pairs -> two float4
    float4* o2 = reinterpret_cast<float4*>(&out2[rowbase * 2]);
    o2[0] = make_float4(xmv[0], ymv[0], xmv[1], ymv[1]);
    o2[1] = make_float4(xmv[2], ymv[2], xmv[3], ymv[3]);

    *reinterpret_cast<float4*>(&out3[rowbase])
        = make_float4(xmv[0], xmv[1], xmv[2], xmv[3]);
    *reinterpret_cast<float4*>(&out4[rowbase])
        = make_float4(ymv[0], ymv[1], ymv[2], ymv[3]);
}

extern "C" void kernel_launch(void* const* d_in, const int* in_sizes, int n_in,
                              void* d_out, int out_size, void* d_ws, size_t ws_size,
                              hipStream_t stream) {
    const float* U     = (const float*)d_in[0];
    const float* theta = (const float*)d_in[1];
    float* out = (float*)d_out;
    float* Hs  = (float*)d_ws;   // 128 * 9 floats

    hipLaunchKernelGGL(hs_kernel, dim3(1), dim3(128), 0, stream, theta, Hs);

    int groups = B_N * H_IMG * GROUPS_X;          // 1,843,200
    int blocks = (groups + 255) / 256;            // 7200
    hipLaunchKernelGGL(warp_kernel, dim3(blocks), dim3(256), 0, stream, U, Hs, out);
}

// Round 8
// 111.298 us; speedup vs baseline: 1.3402x; 1.3402x over previous
//
#include <hip/hip_runtime.h>
#include <math.h>

#pragma clang fp contract(off)

#define B_N   8
#define C_N   3
#define H_IMG 720
#define W_IMG 1280
#define GH    4
#define GW    4
#define CELL_H (H_IMG / GH)   // 180
#define CELL_W (W_IMG / GW)   // 320

// ---------------------------------------------------------------------------
// Kernel 1 (FROZEN numerics — passed R6/R7): netlib sgesv without FMA.
// ---------------------------------------------------------------------------
__global__ void hs_kernel(const float* __restrict__ theta, float* __restrict__ Hs) {
#pragma clang fp contract(off)
    int t = threadIdx.x;
    if (t >= B_N * GH * GW) return;
    int b   = t >> 4;
    int rem = t & 15;
    int i   = rem >> 2;
    int j   = rem & 3;

    float hh = (float)i * 0.5f - 1.0f;
    float ww = (float)j * 0.5f - 1.0f;
    float xs4[4] = { ww, ww + 0.5f, ww, ww + 0.5f };
    float ys4[4] = { hh, hh, hh + 0.5f, hh + 0.5f };
    int ci[4] = { i, i, i + 1, i + 1 };
    int cj[4] = { j, j + 1, j, j + 1 };

    float A[8][8], bv[8];
#pragma unroll
    for (int k = 0; k < 4; ++k) {
        int base = ((b * (GH + 1) + ci[k]) * (GW + 1) + cj[k]) * 2;
        float u = theta[base + 0];
        float v = theta[base + 1];
        float x = xs4[k], y = ys4[k];
        A[k][0] = x;    A[k][1] = y;    A[k][2] = 1.0f;
        A[k][3] = 0.0f; A[k][4] = 0.0f; A[k][5] = 0.0f;
        A[k][6] = -x * u;  A[k][7] = -y * u;
        bv[k] = u;
        A[k+4][0] = 0.0f; A[k+4][1] = 0.0f; A[k+4][2] = 0.0f;
        A[k+4][3] = x;    A[k+4][4] = y;    A[k+4][5] = 1.0f;
        A[k+4][6] = -x * v;  A[k+4][7] = -y * v;
        bv[k+4] = v;
    }
#pragma unroll
    for (int d = 0; d < 8; ++d) A[d][d] = A[d][d] + 1e-4f;

    for (int k = 0; k < 8; ++k) {
        int p = k;
        float pm = fabsf(A[k][k]);
        for (int r = k + 1; r < 8; ++r) {
            float m = fabsf(A[r][k]);
            if (m > pm) { pm = m; p = r; }
        }
        if (p != k) {
            for (int c = 0; c < 8; ++c) {
                float tmp = A[k][c]; A[k][c] = A[p][c]; A[p][c] = tmp;
            }
            float tb = bv[k]; bv[k] = bv[p]; bv[p] = tb;
        }
        float inv = 1.0f / A[k][k];
        for (int r = k + 1; r < 8; ++r) A[r][k] = A[r][k] * inv;
        for (int r = k + 1; r < 8; ++r) {
            float l = A[r][k];
            for (int c = k + 1; c < 8; ++c) A[r][c] = A[r][c] - l * A[k][c];
        }
    }
    for (int k = 0; k < 8; ++k) {
        float bk = bv[k];
        for (int r = k + 1; r < 8; ++r) bv[r] = bv[r] - bk * A[r][k];
    }
    for (int k = 7; k >= 0; --k) {
        bv[k] = bv[k] / A[k][k];
        float bk = bv[k];
        for (int r = 0; r < k; ++r) bv[r] = bv[r] - bk * A[r][k];
    }

    float* o = Hs + t * 9;
#pragma unroll
    for (int k = 0; k < 8; ++k) o[k] = bv[k];
    o[8] = 1.0f;
}

// ---------------------------------------------------------------------------
// Kernel 2: 1 pixel/thread (R6's lane-adjacent gather pattern, FROZEN
// arithmetic), remapped to 2D tiles of 64x4 pixels per block so the 4 rows
// of a tile share bilinear source rows in-cache. 180%4==0 and 320%64==0 so
// no tile straddles a homography cell.
// ---------------------------------------------------------------------------
__global__ __launch_bounds__(256) void warp_kernel(const float* __restrict__ U,
                                                   const float* __restrict__ Hs,
                                                   float* __restrict__ out) {
#pragma clang fp contract(off)
    const int HW = H_IMG * W_IMG;
    int tx = threadIdx.x & 63;        // x within tile
    int ty = threadIdx.x >> 6;        // row within tile
    int x  = blockIdx.x * 64 + tx;
    int y  = blockIdx.y * 4 + ty;
    int b  = blockIdx.z;
    int idx = ((b * H_IMG) + y) * W_IMG + x;

    int ci = y / CELL_H;
    int cj = x / CELL_W;
    const float* Hm = Hs + (((b * GH) + ci) * GW + cj) * 9;
    float h0 = Hm[0], h1 = Hm[1], h2 = Hm[2];
    float h3 = Hm[3], h4 = Hm[4], h5 = Hm[5];
    float h6 = Hm[6], h7 = Hm[7];

    // jax linspace f32 (FROZEN)
    const float DX = 2.0f / 1279.0f;
    const float DY = 2.0f / 719.0f;
    float gx = (x == W_IMG - 1) ? 1.0f : (-1.0f + (float)x * DX);
    float gy = (y == H_IMG - 1) ? 1.0f : (-1.0f + (float)y * DY);

    // einsum f32, non-FMA, left-assoc (FROZEN)
    float X = h0 * gx + h1 * gy + h2;
    float Y = h3 * gx + h4 * gy + h5;
    float Z = h6 * gx + h7 * gy + 1.0f;

    float Zg = Z + ((Z >= 0.0f) ? 1e-8f : -1e-8f);
    float xm = X / Zg;
    float ym = Y / Zg;

    bool oob = (xm < -1.0f) | (xm > 1.0f) | (ym < -1.0f) | (ym > 1.0f);

    float xf = ((xm + 1.0f) * 1280.0f) * 0.5f;
    float yf = ((ym + 1.0f) * 720.0f) * 0.5f;
    int x0 = (int)floorf(xf);
    int y0 = (int)floorf(yf);
    int x1 = x0 + 1;
    int y1 = y0 + 1;
    x0 = min(max(x0, 0), W_IMG - 1);
    x1 = min(max(x1, 0), W_IMG - 1);
    y0 = min(max(y0, 0), H_IMG - 1);
    y1 = min(max(y1, 0), H_IMG - 1);
    float x0f = (float)x0, x1f = (float)x1;
    float y0f = (float)y0, y1f = (float)y1;
    float wa  = (x1f - xf) * (y1f - yf);
    float wb  = (x1f - xf) * (yf - y0f);
    float wcw = (xf - x0f) * (y1f - yf);
    float wd  = (xf - x0f) * (yf - y0f);

    float* out0 = out;
    float* out1 = out + (size_t)B_N * C_N * HW;
    float* out2 = out1 + (size_t)B_N * HW;
    float* out3 = out2 + (size_t)B_N * HW * 2;
    float* out4 = out3 + (size_t)B_N * HW;

    const float* Ub = U + (size_t)b * C_N * HW;
    int ia = y0 * W_IMG + x0;
    int ib = y1 * W_IMG + x0;
    int ic = y0 * W_IMG + x1;
    int id = y1 * W_IMG + x1;
#pragma unroll
    for (int c = 0; c < C_N; ++c) {
        const float* Uc = Ub + (size_t)c * HW;
        float Ia  = Uc[ia];
        float Ibv = Uc[ib];
        float Icv = Uc[ic];
        float Idv = Uc[id];
        // left-assoc f32, no FMA (FROZEN)
        float val = wa * Ia + wb * Ibv + wcw * Icv + wd * Idv;
        out0[(size_t)(b * C_N + c) * HW + (size_t)y * W_IMG + x] = val;
    }
    out1[idx] = oob ? 1.0f : 0.0f;
    float2 xy; xy.x = xm; xy.y = ym;
    reinterpret_cast<float2*>(out2)[idx] = xy;
    out3[idx] = xm;
    out4[idx] = ym;
}

extern "C" void kernel_launch(void* const* d_in, const int* in_sizes, int n_in,
                              void* d_out, int out_size, void* d_ws, size_t ws_size,
                              hipStream_t stream) {
    const float* U     = (const float*)d_in[0];
    const float* theta = (const float*)d_in[1];
    float* out = (float*)d_out;
    float* Hs  = (float*)d_ws;   // 128 * 9 floats

    hipLaunchKernelGGL(hs_kernel, dim3(1), dim3(128), 0, stream, theta, Hs);

    dim3 grid(W_IMG / 64, H_IMG / 4, B_N);   // 20 x 180 x 8
    hipLaunchKernelGGL(warp_kernel, grid, dim3(256), 0, stream, U, Hs, out);
}

// Round 9
// 95.832 us; speedup vs baseline: 1.5565x; 1.1614x over previous
//
#include <hip/hip_runtime.h>
#include <math.h>

#pragma clang fp contract(off)

#define B_N   8
#define C_N   3
#define H_IMG 720
#define W_IMG 1280
#define GH    4
#define GW    4
#define CELL_H (H_IMG / GH)   // 180
#define CELL_W (W_IMG / GW)   // 320

// ---------------------------------------------------------------------------
// Kernel 1 (FROZEN numerics — passed R6/R7/R8): netlib sgesv without FMA.
// ---------------------------------------------------------------------------
__global__ void hs_kernel(const float* __restrict__ theta, float* __restrict__ Hs) {
#pragma clang fp contract(off)
    int t = threadIdx.x;
    if (t >= B_N * GH * GW) return;
    int b   = t >> 4;
    int rem = t & 15;
    int i   = rem >> 2;
    int j   = rem & 3;

    float hh = (float)i * 0.5f - 1.0f;
    float ww = (float)j * 0.5f - 1.0f;
    float xs4[4] = { ww, ww + 0.5f, ww, ww + 0.5f };
    float ys4[4] = { hh, hh, hh + 0.5f, hh + 0.5f };
    int ci[4] = { i, i, i + 1, i + 1 };
    int cj[4] = { j, j + 1, j, j + 1 };

    float A[8][8], bv[8];
#pragma unroll
    for (int k = 0; k < 4; ++k) {
        int base = ((b * (GH + 1) + ci[k]) * (GW + 1) + cj[k]) * 2;
        float u = theta[base + 0];
        float v = theta[base + 1];
        float x = xs4[k], y = ys4[k];
        A[k][0] = x;    A[k][1] = y;    A[k][2] = 1.0f;
        A[k][3] = 0.0f; A[k][4] = 0.0f; A[k][5] = 0.0f;
        A[k][6] = -x * u;  A[k][7] = -y * u;
        bv[k] = u;
        A[k+4][0] = 0.0f; A[k+4][1] = 0.0f; A[k+4][2] = 0.0f;
        A[k+4][3] = x;    A[k+4][4] = y;    A[k+4][5] = 1.0f;
        A[k+4][6] = -x * v;  A[k+4][7] = -y * v;
        bv[k+4] = v;
    }
#pragma unroll
    for (int d = 0; d < 8; ++d) A[d][d] = A[d][d] + 1e-4f;

    for (int k = 0; k < 8; ++k) {
        int p = k;
        float pm = fabsf(A[k][k]);
        for (int r = k + 1; r < 8; ++r) {
            float m = fabsf(A[r][k]);
            if (m > pm) { pm = m; p = r; }
        }
        if (p != k) {
            for (int c = 0; c < 8; ++c) {
                float tmp = A[k][c]; A[k][c] = A[p][c]; A[p][c] = tmp;
            }
            float tb = bv[k]; bv[k] = bv[p]; bv[p] = tb;
        }
        float inv = 1.0f / A[k][k];
        for (int r = k + 1; r < 8; ++r) A[r][k] = A[r][k] * inv;
        for (int r = k + 1; r < 8; ++r) {
            float l = A[r][k];
            for (int c = k + 1; c < 8; ++c) A[r][c] = A[r][c] - l * A[k][c];
        }
    }
    for (int k = 0; k < 8; ++k) {
        float bk = bv[k];
        for (int r = k + 1; r < 8; ++r) bv[r] = bv[r] - bk * A[r][k];
    }
    for (int k = 7; k >= 0; --k) {
        bv[k] = bv[k] / A[k][k];
        float bk = bv[k];
        for (int r = 0; r < k; ++r) bv[r] = bv[r] - bk * A[r][k];
    }

    float* o = Hs + t * 9;
#pragma unroll
    for (int k = 0; k < 8; ++k) o[k] = bv[k];
    o[8] = 1.0f;
}

// ---------------------------------------------------------------------------
// Kernel 2: R6's exact 1D mapping (1 px/thread, 256-thread blocks — best
// measured) with two pure-memory changes:
//  * nontemporal stores for all outputs (never re-read; stop L2 pollution)
//  * x-tap pair loads: one float2 per (row, channel) + branchless select,
//    12 gathers -> 6. Selected values bit-identical to the scalar loads.
// Per-pixel arithmetic FROZEN (JAX-f32 semantics, passed R6/R7/R8).
// ---------------------------------------------------------------------------
__global__ __launch_bounds__(256) void warp_kernel(const float* __restrict__ U,
                                                   const float* __restrict__ Hs,
                                                   float* __restrict__ out) {
#pragma clang fp contract(off)
    const int HW = H_IMG * W_IMG;
    int idx = blockIdx.x * 256 + threadIdx.x;
    if (idx >= B_N * HW) return;

    int x = idx % W_IMG;
    int t = idx / W_IMG;
    int y = t % H_IMG;
    int b = t / H_IMG;

    int ci = y / CELL_H;
    int cj = x / CELL_W;
    const float* Hm = Hs + (((b * GH) + ci) * GW + cj) * 9;
    float h0 = Hm[0], h1 = Hm[1], h2 = Hm[2];
    float h3 = Hm[3], h4 = Hm[4], h5 = Hm[5];
    float h6 = Hm[6], h7 = Hm[7];

    // jax linspace f32 (FROZEN)
    const float DX = 2.0f / 1279.0f;
    const float DY = 2.0f / 719.0f;
    float gx = (x == W_IMG - 1) ? 1.0f : (-1.0f + (float)x * DX);
    float gy = (y == H_IMG - 1) ? 1.0f : (-1.0f + (float)y * DY);

    // einsum f32, non-FMA, left-assoc (FROZEN)
    float X = h0 * gx + h1 * gy + h2;
    float Y = h3 * gx + h4 * gy + h5;
    float Z = h6 * gx + h7 * gy + 1.0f;

    float Zg = Z + ((Z >= 0.0f) ? 1e-8f : -1e-8f);
    float xm = X / Zg;
    float ym = Y / Zg;

    bool oob = (xm < -1.0f) | (xm > 1.0f) | (ym < -1.0f) | (ym > 1.0f);

    float xf = ((xm + 1.0f) * 1280.0f) * 0.5f;
    float yf = ((ym + 1.0f) * 720.0f) * 0.5f;
    int x0 = (int)floorf(xf);
    int y0 = (int)floorf(yf);
    int x1 = x0 + 1;
    int y1 = y0 + 1;
    x0 = min(max(x0, 0), W_IMG - 1);
    x1 = min(max(x1, 0), W_IMG - 1);
    y0 = min(max(y0, 0), H_IMG - 1);
    y1 = min(max(y1, 0), H_IMG - 1);
    float x0f = (float)x0, x1f = (float)x1;
    float y0f = (float)y0, y1f = (float)y1;
    float wa  = (x1f - xf) * (y1f - yf);
    float wb  = (x1f - xf) * (yf - y0f);
    float wcw = (xf - x0f) * (y1f - yf);
    float wd  = (xf - x0f) * (y1f - y0f - (y1f - yf));   // = (xf-x0f)*(yf-y0f)
    // NOTE: keep wd exactly as reference form:
    wd = (xf - x0f) * (yf - y0f);

    // paired x-taps: base column xb, offsets in {0,1} select identical values
    int xb = min(x0, W_IMG - 2);          // x0 already >= 0
    int offa = x0 - xb;                   // 0 or 1
    int offc = x1 - xb;                   // 0 or 1

    float* out0 = out;
    float* out1 = out + (size_t)B_N * C_N * HW;
    float* out2 = out1 + (size_t)B_N * HW;
    float* out3 = out2 + (size_t)B_N * HW * 2;
    float* out4 = out3 + (size_t)B_N * HW;

    const float* Ub = U + (size_t)b * C_N * HW;
    int rowA = y0 * W_IMG + xb;
    int rowB = y1 * W_IMG + xb;
#pragma unroll
    for (int c = 0; c < C_N; ++c) {
        const float* Uc = Ub + (size_t)c * HW;
        float2 pA = *reinterpret_cast<const float2*>(&Uc[rowA]);
        float2 pB = *reinterpret_cast<const float2*>(&Uc[rowB]);
        float Ia  = offa ? pA.y : pA.x;
        float Ibv = offa ? pB.y : pB.x;
        float Icv = offc ? pA.y : pA.x;
        float Idv = offc ? pB.y : pB.x;
        // left-assoc f32, no FMA (FROZEN)
        float val = wa * Ia + wb * Ibv + wcw * Icv + wd * Idv;
        __builtin_nontemporal_store(val,
            &out0[(size_t)(b * C_N + c) * HW + (size_t)y * W_IMG + x]);
    }
    __builtin_nontemporal_store(oob ? 1.0f : 0.0f, &out1[idx]);

    // out2 pair (xm,ym) as one 8B NT store (region is 8B aligned)
    union { float2 f2; double d; } u2;
    u2.f2.x = xm; u2.f2.y = ym;
    __builtin_nontemporal_store(u2.d, &reinterpret_cast<double*>(out2)[idx]);

    __builtin_nontemporal_store(xm, &out3[idx]);
    __builtin_nontemporal_store(ym, &out4[idx]);
}

extern "C" void kernel_launch(void* const* d_in, const int* in_sizes, int n_in,
                              void* d_out, int out_size, void* d_ws, size_t ws_size,
                              hipStream_t stream) {
    const float* U     = (const float*)d_in[0];
    const float* theta = (const float*)d_in[1];
    float* out = (float*)d_out;
    float* Hs  = (float*)d_ws;   // 128 * 9 floats

    hipLaunchKernelGGL(hs_kernel, dim3(1), dim3(128), 0, stream, theta, Hs);

    int total = B_N * H_IMG * W_IMG;
    int blocks = (total + 255) / 256;   // 28800
    hipLaunchKernelGGL(warp_kernel, dim3(blocks), dim3(256), 0, stream, U, Hs, out);
}

// Round 10
// 65.992 us; speedup vs baseline: 2.2603x; 1.4522x over previous
//
#include <hip/hip_runtime.h>
#include <math.h>

#pragma clang fp contract(off)

#define B_N   8
#define C_N   3
#define H_IMG 720
#define W_IMG 1280
#define GH    4
#define GW    4
#define CELL_H (H_IMG / GH)   // 180
#define CELL_W (W_IMG / GW)   // 320

// ---------------------------------------------------------------------------
// Kernel 1 (FROZEN numerics — passed R6-R9): netlib sgesv without FMA.
// ---------------------------------------------------------------------------
__global__ void hs_kernel(const float* __restrict__ theta, float* __restrict__ Hs) {
#pragma clang fp contract(off)
    int t = threadIdx.x;
    if (t >= B_N * GH * GW) return;
    int b   = t >> 4;
    int rem = t & 15;
    int i   = rem >> 2;
    int j   = rem & 3;

    float hh = (float)i * 0.5f - 1.0f;
    float ww = (float)j * 0.5f - 1.0f;
    float xs4[4] = { ww, ww + 0.5f, ww, ww + 0.5f };
    float ys4[4] = { hh, hh, hh + 0.5f, hh + 0.5f };
    int ci[4] = { i, i, i + 1, i + 1 };
    int cj[4] = { j, j + 1, j, j + 1 };

    float A[8][8], bv[8];
#pragma unroll
    for (int k = 0; k < 4; ++k) {
        int base = ((b * (GH + 1) + ci[k]) * (GW + 1) + cj[k]) * 2;
        float u = theta[base + 0];
        float v = theta[base + 1];
        float x = xs4[k], y = ys4[k];
        A[k][0] = x;    A[k][1] = y;    A[k][2] = 1.0f;
        A[k][3] = 0.0f; A[k][4] = 0.0f; A[k][5] = 0.0f;
        A[k][6] = -x * u;  A[k][7] = -y * u;
        bv[k] = u;
        A[k+4][0] = 0.0f; A[k+4][1] = 0.0f; A[k+4][2] = 0.0f;
        A[k+4][3] = x;    A[k+4][4] = y;    A[k+4][5] = 1.0f;
        A[k+4][6] = -x * v;  A[k+4][7] = -y * v;
        bv[k+4] = v;
    }
#pragma unroll
    for (int d = 0; d < 8; ++d) A[d][d] = A[d][d] + 1e-4f;

    for (int k = 0; k < 8; ++k) {
        int p = k;
        float pm = fabsf(A[k][k]);
        for (int r = k + 1; r < 8; ++r) {
            float m = fabsf(A[r][k]);
            if (m > pm) { pm = m; p = r; }
        }
        if (p != k) {
            for (int c = 0; c < 8; ++c) {
                float tmp = A[k][c]; A[k][c] = A[p][c]; A[p][c] = tmp;
            }
            float tb = bv[k]; bv[k] = bv[p]; bv[p] = tb;
        }
        float inv = 1.0f / A[k][k];
        for (int r = k + 1; r < 8; ++r) A[r][k] = A[r][k] * inv;
        for (int r = k + 1; r < 8; ++r) {
            float l = A[r][k];
            for (int c = k + 1; c < 8; ++c) A[r][c] = A[r][c] - l * A[k][c];
        }
    }
    for (int k = 0; k < 8; ++k) {
        float bk = bv[k];
        for (int r = k + 1; r < 8; ++r) bv[r] = bv[r] - bk * A[r][k];
    }
    for (int k = 7; k >= 0; --k) {
        bv[k] = bv[k] / A[k][k];
        float bk = bv[k];
        for (int r = 0; r < k; ++r) bv[r] = bv[r] - bk * A[r][k];
    }

    float* o = Hs + t * 9;
#pragma unroll
    for (int k = 0; k < 8; ++k) o[k] = bv[k];
    o[8] = 1.0f;
}

// ---------------------------------------------------------------------------
// Kernel 2: R9 exactly (1 px/thread, NT stores, paired x-tap loads, FROZEN
// JAX-f32 arithmetic) + XCD-aware block swizzle: physical block P -> logical
// block (P%8)*(nwg/8) + P/8, so each XCD owns one contiguous image slab and
// adjacent output rows (which share bilinear source rows) stay in the same
// XCD's L2. nwg = 28800 (divisible by 8 -> bijective).
// ---------------------------------------------------------------------------
__global__ __launch_bounds__(256) void warp_kernel(const float* __restrict__ U,
                                                   const float* __restrict__ Hs,
                                                   float* __restrict__ out) {
#pragma clang fp contract(off)
    const int HW = H_IMG * W_IMG;
    // XCD swizzle: 28800 blocks, 8 XCDs, 3600 blocks/XCD slab
    int lb = (blockIdx.x & 7) * ((int)gridDim.x >> 3) + ((int)blockIdx.x >> 3);
    int idx = lb * 256 + threadIdx.x;

    int x = idx % W_IMG;
    int t = idx / W_IMG;
    int y = t % H_IMG;
    int b = t / H_IMG;

    int ci = y / CELL_H;
    int cj = x / CELL_W;
    const float* Hm = Hs + (((b * GH) + ci) * GW + cj) * 9;
    float h0 = Hm[0], h1 = Hm[1], h2 = Hm[2];
    float h3 = Hm[3], h4 = Hm[4], h5 = Hm[5];
    float h6 = Hm[6], h7 = Hm[7];

    // jax linspace f32 (FROZEN)
    const float DX = 2.0f / 1279.0f;
    const float DY = 2.0f / 719.0f;
    float gx = (x == W_IMG - 1) ? 1.0f : (-1.0f + (float)x * DX);
    float gy = (y == H_IMG - 1) ? 1.0f : (-1.0f + (float)y * DY);

    // einsum f32, non-FMA, left-assoc (FROZEN)
    float X = h0 * gx + h1 * gy + h2;
    float Y = h3 * gx + h4 * gy + h5;
    float Z = h6 * gx + h7 * gy + 1.0f;

    float Zg = Z + ((Z >= 0.0f) ? 1e-8f : -1e-8f);
    float xm = X / Zg;
    float ym = Y / Zg;

    bool oob = (xm < -1.0f) | (xm > 1.0f) | (ym < -1.0f) | (ym > 1.0f);

    float xf = ((xm + 1.0f) * 1280.0f) * 0.5f;
    float yf = ((ym + 1.0f) * 720.0f) * 0.5f;
    int x0 = (int)floorf(xf);
    int y0 = (int)floorf(yf);
    int x1 = x0 + 1;
    int y1 = y0 + 1;
    x0 = min(max(x0, 0), W_IMG - 1);
    x1 = min(max(x1, 0), W_IMG - 1);
    y0 = min(max(y0, 0), H_IMG - 1);
    y1 = min(max(y1, 0), H_IMG - 1);
    float x0f = (float)x0, x1f = (float)x1;
    float y0f = (float)y0, y1f = (float)y1;
    float wa  = (x1f - xf) * (y1f - yf);
    float wb  = (x1f - xf) * (yf - y0f);
    float wcw = (xf - x0f) * (y1f - yf);
    float wd  = (xf - x0f) * (yf - y0f);

    // paired x-taps: base column xb, offsets in {0,1} select identical values
    int xb = min(x0, W_IMG - 2);          // x0 already >= 0
    int offa = x0 - xb;                   // 0 or 1
    int offc = x1 - xb;                   // 0 or 1

    float* out0 = out;
    float* out1 = out + (size_t)B_N * C_N * HW;
    float* out2 = out1 + (size_t)B_N * HW;
    float* out3 = out2 + (size_t)B_N * HW * 2;
    float* out4 = out3 + (size_t)B_N * HW;

    const float* Ub = U + (size_t)b * C_N * HW;
    int rowA = y0 * W_IMG + xb;
    int rowB = y1 * W_IMG + xb;
#pragma unroll
    for (int c = 0; c < C_N; ++c) {
        const float* Uc = Ub + (size_t)c * HW;
        float2 pA = *reinterpret_cast<const float2*>(&Uc[rowA]);
        float2 pB = *reinterpret_cast<const float2*>(&Uc[rowB]);
        float Ia  = offa ? pA.y : pA.x;
        float Ibv = offa ? pB.y : pB.x;
        float Icv = offc ? pA.y : pA.x;
        float Idv = offc ? pB.y : pB.x;
        // left-assoc f32, no FMA (FROZEN)
        float val = wa * Ia + wb * Ibv + wcw * Icv + wd * Idv;
        __builtin_nontemporal_store(val,
            &out0[(size_t)(b * C_N + c) * HW + (size_t)y * W_IMG + x]);
    }
    __builtin_nontemporal_store(oob ? 1.0f : 0.0f, &out1[idx]);

    union { float2 f2; double d; } u2;
    u2.f2.x = xm; u2.f2.y = ym;
    __builtin_nontemporal_store(u2.d, &reinterpret_cast<double*>(out2)[idx]);

    __builtin_nontemporal_store(xm, &out3[idx]);
    __builtin_nontemporal_store(ym, &out4[idx]);
}

extern "C" void kernel_launch(void* const* d_in, const int* in_sizes, int n_in,
                              void* d_out, int out_size, void* d_ws, size_t ws_size,
                              hipStream_t stream) {
    const float* U     = (const float*)d_in[0];
    const float* theta = (const float*)d_in[1];
    float* out = (float*)d_out;
    float* Hs  = (float*)d_ws;   // 128 * 9 floats

    hipLaunchKernelGGL(hs_kernel, dim3(1), dim3(128), 0, stream, theta, Hs);

    int total = B_N * H_IMG * W_IMG;
    int blocks = (total + 255) / 256;   // 28800, divisible by 8
    hipLaunchKernelGGL(warp_kernel, dim3(blocks), dim3(256), 0, stream, U, Hs, out);
}

// Round 11
// 64.913 us; speedup vs baseline: 2.2979x; 1.0166x over previous
//
#include <hip/hip_runtime.h>
#include <math.h>

#pragma clang fp contract(off)

#define B_N   8
#define C_N   3
#define H_IMG 720
#define W_IMG 1280
#define GH    4
#define GW    4
#define CELL_H (H_IMG / GH)   // 180
#define CELL_W (W_IMG / GW)   // 320

typedef float v2f __attribute__((ext_vector_type(2)));
typedef float v4f __attribute__((ext_vector_type(4)));

// ---------------------------------------------------------------------------
// Kernel 1 (FROZEN numerics — passed R6-R10): netlib sgesv without FMA.
// ---------------------------------------------------------------------------
__global__ void hs_kernel(const float* __restrict__ theta, float* __restrict__ Hs) {
#pragma clang fp contract(off)
    int t = threadIdx.x;
    if (t >= B_N * GH * GW) return;
    int b   = t >> 4;
    int rem = t & 15;
    int i   = rem >> 2;
    int j   = rem & 3;

    float hh = (float)i * 0.5f - 1.0f;
    float ww = (float)j * 0.5f - 1.0f;
    float xs4[4] = { ww, ww + 0.5f, ww, ww + 0.5f };
    float ys4[4] = { hh, hh, hh + 0.5f, hh + 0.5f };
    int ci[4] = { i, i, i + 1, i + 1 };
    int cj[4] = { j, j + 1, j, j + 1 };

    float A[8][8], bv[8];
#pragma unroll
    for (int k = 0; k < 4; ++k) {
        int base = ((b * (GH + 1) + ci[k]) * (GW + 1) + cj[k]) * 2;
        float u = theta[base + 0];
        float v = theta[base + 1];
        float x = xs4[k], y = ys4[k];
        A[k][0] = x;    A[k][1] = y;    A[k][2] = 1.0f;
        A[k][3] = 0.0f; A[k][4] = 0.0f; A[k][5] = 0.0f;
        A[k][6] = -x * u;  A[k][7] = -y * u;
        bv[k] = u;
        A[k+4][0] = 0.0f; A[k+4][1] = 0.0f; A[k+4][2] = 0.0f;
        A[k+4][3] = x;    A[k+4][4] = y;    A[k+4][5] = 1.0f;
        A[k+4][6] = -x * v;  A[k+4][7] = -y * v;
        bv[k+4] = v;
    }
#pragma unroll
    for (int d = 0; d < 8; ++d) A[d][d] = A[d][d] + 1e-4f;

    for (int k = 0; k < 8; ++k) {
        int p = k;
        float pm = fabsf(A[k][k]);
        for (int r = k + 1; r < 8; ++r) {
            float m = fabsf(A[r][k]);
            if (m > pm) { pm = m; p = r; }
        }
        if (p != k) {
            for (int c = 0; c < 8; ++c) {
                float tmp = A[k][c]; A[k][c] = A[p][c]; A[p][c] = tmp;
            }
            float tb = bv[k]; bv[k] = bv[p]; bv[p] = tb;
        }
        float inv = 1.0f / A[k][k];
        for (int r = k + 1; r < 8; ++r) A[r][k] = A[r][k] * inv;
        for (int r = k + 1; r < 8; ++r) {
            float l = A[r][k];
            for (int c = k + 1; c < 8; ++c) A[r][c] = A[r][c] - l * A[k][c];
        }
    }
    for (int k = 0; k < 8; ++k) {
        float bk = bv[k];
        for (int r = k + 1; r < 8; ++r) bv[r] = bv[r] - bk * A[r][k];
    }
    for (int k = 7; k >= 0; --k) {
        bv[k] = bv[k] / A[k][k];
        float bk = bv[k];
        for (int r = 0; r < k; ++r) bv[r] = bv[r] - bk * A[r][k];
    }

    float* o = Hs + t * 9;
#pragma unroll
    for (int k = 0; k < 8; ++k) o[k] = bv[k];
    o[8] = 1.0f;
}

// ---------------------------------------------------------------------------
// Kernel 2: 2 px/thread along x (lane footprint 8B), XCD swizzle, NT vector
// stores (float2/float4), per-pixel paired x-tap float2 gathers. Per-pixel
// arithmetic FROZEN (JAX-f32 semantics, bit-identical to R6-R10 PASS).
// ---------------------------------------------------------------------------
#define HALFW (W_IMG / 2)   // 640

__global__ __launch_bounds__(256) void warp_kernel(const float* __restrict__ U,
                                                   const float* __restrict__ Hs,
                                                   float* __restrict__ out) {
#pragma clang fp contract(off)
    const int HW = H_IMG * W_IMG;
    // XCD swizzle: 14400 blocks, 8 XCDs, 1800 blocks/XCD slab
    int lb = (blockIdx.x & 7) * ((int)gridDim.x >> 3) + ((int)blockIdx.x >> 3);
    int g  = lb * 256 + threadIdx.x;       // pair index

    int xp2 = g % HALFW;
    int t   = g / HALFW;                   // t = b*H + y
    int y   = t % H_IMG;
    int b   = t / H_IMG;
    int xp  = xp2 * 2;                     // first pixel x (even)

    int ci = y / CELL_H;
    int cj = xp / CELL_W;                  // same cell for both px
    const float* Hm = Hs + (((b * GH) + ci) * GW + cj) * 9;
    float h0 = Hm[0], h1 = Hm[1], h2 = Hm[2];
    float h3 = Hm[3], h4 = Hm[4], h5 = Hm[5];
    float h6 = Hm[6], h7 = Hm[7];

    const float DX = 2.0f / 1279.0f;
    const float DY = 2.0f / 719.0f;
    float gy = (y == H_IMG - 1) ? 1.0f : (-1.0f + (float)y * DY);

    const float* Ub = U + (size_t)b * C_N * HW;

    float xmv[2], ymv[2], oobv[2];
    float cv[C_N][2];

#pragma unroll
    for (int k = 0; k < 2; ++k) {
        int x = xp + k;
        float gx = (x == W_IMG - 1) ? 1.0f : (-1.0f + (float)x * DX);

        // einsum f32, non-FMA, left-assoc (FROZEN)
        float X = h0 * gx + h1 * gy + h2;
        float Y = h3 * gx + h4 * gy + h5;
        float Z = h6 * gx + h7 * gy + 1.0f;

        float Zg = Z + ((Z >= 0.0f) ? 1e-8f : -1e-8f);
        float xm = X / Zg;
        float ym = Y / Zg;
        xmv[k] = xm;
        ymv[k] = ym;
        oobv[k] = ((xm < -1.0f) | (xm > 1.0f) | (ym < -1.0f) | (ym > 1.0f))
                      ? 1.0f : 0.0f;

        float xf = ((xm + 1.0f) * 1280.0f) * 0.5f;
        float yf = ((ym + 1.0f) * 720.0f) * 0.5f;
        int x0 = (int)floorf(xf);
        int y0 = (int)floorf(yf);
        int x1 = x0 + 1;
        int y1 = y0 + 1;
        x0 = min(max(x0, 0), W_IMG - 1);
        x1 = min(max(x1, 0), W_IMG - 1);
        y0 = min(max(y0, 0), H_IMG - 1);
        y1 = min(max(y1, 0), H_IMG - 1);
        float x0f = (float)x0, x1f = (float)x1;
        float y0f = (float)y0, y1f = (float)y1;
        float wa  = (x1f - xf) * (y1f - yf);
        float wb  = (x1f - xf) * (yf - y0f);
        float wcw = (xf - x0f) * (y1f - yf);
        float wd  = (xf - x0f) * (yf - y0f);

        int xb   = min(x0, W_IMG - 2);
        int offa = x0 - xb;
        int offc = x1 - xb;
        int rowA = y0 * W_IMG + xb;
        int rowB = y1 * W_IMG + xb;

#pragma unroll
        for (int c = 0; c < C_N; ++c) {
            const float* Uc = Ub + (size_t)c * HW;
            float2 pA = *reinterpret_cast<const float2*>(&Uc[rowA]);
            float2 pB = *reinterpret_cast<const float2*>(&Uc[rowB]);
            float Ia  = offa ? pA.y : pA.x;
            float Ibv = offa ? pB.y : pB.x;
            float Icv = offc ? pA.y : pA.x;
            float Idv = offc ? pB.y : pB.x;
            // left-assoc f32, no FMA (FROZEN)
            cv[c][k] = wa * Ia + wb * Ibv + wcw * Icv + wd * Idv;
        }
    }

    float* out0 = out;
    float* out1 = out + (size_t)B_N * C_N * HW;
    float* out2 = out1 + (size_t)B_N * HW;
    float* out3 = out2 + (size_t)B_N * HW * 2;
    float* out4 = out3 + (size_t)B_N * HW;

    size_t rowpix = (size_t)t * W_IMG + xp;   // pixel index of px0 (even)

#pragma unroll
    for (int c = 0; c < C_N; ++c) {
        v2f v; v.x = cv[c][0]; v.y = cv[c][1];
        __builtin_nontemporal_store(v,
            (v2f*)&out0[(size_t)(b * C_N + c) * HW + (size_t)y * W_IMG + xp]);
    }
    {
        v2f v; v.x = oobv[0]; v.y = oobv[1];
        __builtin_nontemporal_store(v, (v2f*)&out1[rowpix]);
    }
    {
        v4f v; v.x = xmv[0]; v.y = ymv[0]; v.z = xmv[1]; v.w = ymv[1];
        __builtin_nontemporal_store(v, (v4f*)&out2[rowpix * 2]);
    }
    {
        v2f v; v.x = xmv[0]; v.y = xmv[1];
        __builtin_nontemporal_store(v, (v2f*)&out3[rowpix]);
    }
    {
        v2f v; v.x = ymv[0]; v.y = ymv[1];
        __builtin_nontemporal_store(v, (v2f*)&out4[rowpix]);
    }
}

extern "C" void kernel_launch(void* const* d_in, const int* in_sizes, int n_in,
                              void* d_out, int out_size, void* d_ws, size_t ws_size,
                              hipStream_t stream) {
    const float* U     = (const float*)d_in[0];
    const float* theta = (const float*)d_in[1];
    float* out = (float*)d_out;
    float* Hs  = (float*)d_ws;   // 128 * 9 floats

    hipLaunchKernelGGL(hs_kernel, dim3(1), dim3(128), 0, stream, theta, Hs);

    int pairs  = B_N * H_IMG * HALFW;        // 3,686,400
    int blocks = pairs / 256;                // 14400, divisible by 8
    hipLaunchKernelGGL(warp_kernel, dim3(blocks), dim3(256), 0, stream, U, Hs, out);
}

// Round 12
// 64.250 us; speedup vs baseline: 2.3216x; 1.0103x over previous
//
#include <hip/hip_runtime.h>
#include <math.h>

#pragma clang fp contract(off)

#define B_N   8
#define C_N   3
#define H_IMG 720
#define W_IMG 1280
#define GH    4
#define GW    4
#define CELL_H (H_IMG / GH)   // 180
#define CELL_W (W_IMG / GW)   // 320

// ---------------------------------------------------------------------------
// Kernel 1 (FROZEN numerics — passed R6-R11): netlib sgesv without FMA.
// ---------------------------------------------------------------------------
__global__ void hs_kernel(const float* __restrict__ theta, float* __restrict__ Hs) {
#pragma clang fp contract(off)
    int t = threadIdx.x;
    if (t >= B_N * GH * GW) return;
    int b   = t >> 4;
    int rem = t & 15;
    int i   = rem >> 2;
    int j   = rem & 3;

    float hh = (float)i * 0.5f - 1.0f;
    float ww = (float)j * 0.5f - 1.0f;
    float xs4[4] = { ww, ww + 0.5f, ww, ww + 0.5f };
    float ys4[4] = { hh, hh, hh + 0.5f, hh + 0.5f };
    int ci[4] = { i, i, i + 1, i + 1 };
    int cj[4] = { j, j + 1, j, j + 1 };

    float A[8][8], bv[8];
#pragma unroll
    for (int k = 0; k < 4; ++k) {
        int base = ((b * (GH + 1) + ci[k]) * (GW + 1) + cj[k]) * 2;
        float u = theta[base + 0];
        float v = theta[base + 1];
        float x = xs4[k], y = ys4[k];
        A[k][0] = x;    A[k][1] = y;    A[k][2] = 1.0f;
        A[k][3] = 0.0f; A[k][4] = 0.0f; A[k][5] = 0.0f;
        A[k][6] = -x * u;  A[k][7] = -y * u;
        bv[k] = u;
        A[k+4][0] = 0.0f; A[k+4][1] = 0.0f; A[k+4][2] = 0.0f;
        A[k+4][3] = x;    A[k+4][4] = y;    A[k+4][5] = 1.0f;
        A[k+4][6] = -x * v;  A[k+4][7] = -y * v;
        bv[k+4] = v;
    }
#pragma unroll
    for (int d = 0; d < 8; ++d) A[d][d] = A[d][d] + 1e-4f;

    for (int k = 0; k < 8; ++k) {
        int p = k;
        float pm = fabsf(A[k][k]);
        for (int r = k + 1; r < 8; ++r) {
            float m = fabsf(A[r][k]);
            if (m > pm) { pm = m; p = r; }
        }
        if (p != k) {
            for (int c = 0; c < 8; ++c) {
                float tmp = A[k][c]; A[k][c] = A[p][c]; A[p][c] = tmp;
            }
            float tb = bv[k]; bv[k] = bv[p]; bv[p] = tb;
        }
        float inv = 1.0f / A[k][k];
        for (int r = k + 1; r < 8; ++r) A[r][k] = A[r][k] * inv;
        for (int r = k + 1; r < 8; ++r) {
            float l = A[r][k];
            for (int c = k + 1; c < 8; ++c) A[r][c] = A[r][c] - l * A[k][c];
        }
    }
    for (int k = 0; k < 8; ++k) {
        float bk = bv[k];
        for (int r = k + 1; r < 8; ++r) bv[r] = bv[r] - bk * A[r][k];
    }
    for (int k = 7; k >= 0; --k) {
        bv[k] = bv[k] / A[k][k];
        float bk = bv[k];
        for (int r = 0; r < k; ++r) bv[r] = bv[r] - bk * A[r][k];
    }

    float* o = Hs + t * 9;
#pragma unroll
    for (int k = 0; k < 8; ++k) o[k] = bv[k];
    o[8] = 1.0f;
}

// ---------------------------------------------------------------------------
// Kernel 2: 2 px/thread VERTICALLY (x, y) and (x, y+1) — the bilinear source
// row shared by the two pixels is read back-to-back by the same thread
// (guaranteed L1 hit -> no HBM re-fetch), lane pitch in x stays 4B.
// XCD swizzle (each XCD = one image), NT stores, paired x-tap float2 loads.
// Per-pixel arithmetic FROZEN (JAX-f32 semantics, bit-identical since R6).
// ---------------------------------------------------------------------------
#define HALFH (H_IMG / 2)   // 360

__global__ __launch_bounds__(256) void warp_kernel(const float* __restrict__ U,
                                                   const float* __restrict__ Hs,
                                                   float* __restrict__ out) {
#pragma clang fp contract(off)
    const int HW = H_IMG * W_IMG;
    // XCD swizzle: 14400 blocks, 8 XCDs, 1800 blocks/XCD = exactly 1 image
    int lb = (blockIdx.x & 7) * ((int)gridDim.x >> 3) + ((int)blockIdx.x >> 3);
    int g  = lb * 256 + threadIdx.x;       // pair index

    int x   = g % W_IMG;
    int t2  = g / W_IMG;                   // t2 = b*HALFH + yh
    int yh  = t2 % HALFH;
    int b   = t2 / HALFH;
    int yp  = yh * 2;                      // first row y (even)

    // both rows are in the same cell row (CELL_H=180 even)
    int ci = yp / CELL_H;
    int cj = x / CELL_W;
    const float* Hm = Hs + (((b * GH) + ci) * GW + cj) * 9;
    float h0 = Hm[0], h1 = Hm[1], h2 = Hm[2];
    float h3 = Hm[3], h4 = Hm[4], h5 = Hm[5];
    float h6 = Hm[6], h7 = Hm[7];

    const float DX = 2.0f / 1279.0f;
    const float DY = 2.0f / 719.0f;
    float gx = (x == W_IMG - 1) ? 1.0f : (-1.0f + (float)x * DX);

    const float* Ub = U + (size_t)b * C_N * HW;

    float xmv[2], ymv[2], oobv[2];
    float cv[C_N][2];

#pragma unroll
    for (int k = 0; k < 2; ++k) {
        int y = yp + k;
        float gy = (y == H_IMG - 1) ? 1.0f : (-1.0f + (float)y * DY);

        // einsum f32, non-FMA, left-assoc (FROZEN)
        float X = h0 * gx + h1 * gy + h2;
        float Y = h3 * gx + h4 * gy + h5;
        float Z = h6 * gx + h7 * gy + 1.0f;

        float Zg = Z + ((Z >= 0.0f) ? 1e-8f : -1e-8f);
        float xm = X / Zg;
        float ym = Y / Zg;
        xmv[k] = xm;
        ymv[k] = ym;
        oobv[k] = ((xm < -1.0f) | (xm > 1.0f) | (ym < -1.0f) | (ym > 1.0f))
                      ? 1.0f : 0.0f;

        float xf = ((xm + 1.0f) * 1280.0f) * 0.5f;
        float yf = ((ym + 1.0f) * 720.0f) * 0.5f;
        int x0 = (int)floorf(xf);
        int y0 = (int)floorf(yf);
        int x1 = x0 + 1;
        int y1 = y0 + 1;
        x0 = min(max(x0, 0), W_IMG - 1);
        x1 = min(max(x1, 0), W_IMG - 1);
        y0 = min(max(y0, 0), H_IMG - 1);
        y1 = min(max(y1, 0), H_IMG - 1);
        float x0f = (float)x0, x1f = (float)x1;
        float y0f = (float)y0, y1f = (float)y1;
        float wa  = (x1f - xf) * (y1f - yf);
        float wb  = (x1f - xf) * (yf - y0f);
        float wcw = (xf - x0f) * (y1f - yf);
        float wd  = (xf - x0f) * (yf - y0f);

        int xb   = min(x0, W_IMG - 2);
        int offa = x0 - xb;
        int offc = x1 - xb;
        int rowA = y0 * W_IMG + xb;
        int rowB = y1 * W_IMG + xb;

#pragma unroll
        for (int c = 0; c < C_N; ++c) {
            const float* Uc = Ub + (size_t)c * HW;
            float2 pA = *reinterpret_cast<const float2*>(&Uc[rowA]);
            float2 pB = *reinterpret_cast<const float2*>(&Uc[rowB]);
            float Ia  = offa ? pA.y : pA.x;
            float Ibv = offa ? pB.y : pB.x;
            float Icv = offc ? pA.y : pA.x;
            float Idv = offc ? pB.y : pB.x;
            // left-assoc f32, no FMA (FROZEN)
            cv[c][k] = wa * Ia + wb * Ibv + wcw * Icv + wd * Idv;
        }
    }

    float* out0 = out;
    float* out1 = out + (size_t)B_N * C_N * HW;
    float* out2 = out1 + (size_t)B_N * HW;
    float* out3 = out2 + (size_t)B_N * HW * 2;
    float* out4 = out3 + (size_t)B_N * HW;

#pragma unroll
    for (int k = 0; k < 2; ++k) {
        int y = yp + k;
        size_t pix = ((size_t)b * H_IMG + y) * W_IMG + x;
#pragma unroll
        for (int c = 0; c < C_N; ++c) {
            __builtin_nontemporal_store(cv[c][k],
                &out0[(size_t)(b * C_N + c) * HW + (size_t)y * W_IMG + x]);
        }
        __builtin_nontemporal_store(oobv[k], &out1[pix]);
        union { float2 f2; double d; } u2;
        u2.f2.x = xmv[k]; u2.f2.y = ymv[k];
        __builtin_nontemporal_store(u2.d, &reinterpret_cast<double*>(out2)[pix]);
        __builtin_nontemporal_store(xmv[k], &out3[pix]);
        __builtin_nontemporal_store(ymv[k], &out4[pix]);
    }
}

extern "C" void kernel_launch(void* const* d_in, const int* in_sizes, int n_in,
                              void* d_out, int out_size, void* d_ws, size_t ws_size,
                              hipStream_t stream) {
    const float* U     = (const float*)d_in[0];
    const float* theta = (const float*)d_in[1];
    float* out = (float*)d_out;
    float* Hs  = (float*)d_ws;   // 128 * 9 floats

    hipLaunchKernelGGL(hs_kernel, dim3(1), dim3(128), 0, stream, theta, Hs);

    int pairs  = B_N * HALFH * W_IMG;        // 3,686,400
    int blocks = pairs / 256;                // 14400, divisible by 8
    hipLaunchKernelGGL(warp_kernel, dim3(blocks), dim3(256), 0, stream, U, Hs, out);
}